// Round 6
// baseline (317.242 us; speedup 1.0000x reference)
//
#include <hip/hip_runtime.h>
#include <math.h>

// Problem constants
#define TBR  131072      // 64*2048 rows
#define OBS  512
#define H1N  400
#define H2N  300
#define CORE 302

// Geometry: M=128 rows/block, 1024 threads (16 waves), 1 block/CU.
#define BM     128
#define NTH    1024
#define CH_K   64        // frame K-chunk
#define NCHUNK 8         // OBS / CH_K
#define CH_S   64        // chunk stride (exact; XOR-swizzled, T2)
#define H1_S   424       // h1/core stride (K padded 400->416, head pad ->320)

typedef __bf16 bf16x8 __attribute__((ext_vector_type(8)));
typedef __bf16 bf16x4 __attribute__((ext_vector_type(4)));
typedef float  f32x4  __attribute__((ext_vector_type(4)));

__device__ __forceinline__ bf16x8 cvt8(float4 a, float4 b) {
    bf16x8 v;
    v[0] = (__bf16)a.x; v[1] = (__bf16)a.y; v[2] = (__bf16)a.z; v[3] = (__bf16)a.w;
    v[4] = (__bf16)b.x; v[5] = (__bf16)b.y; v[6] = (__bf16)b.z; v[7] = (__bf16)b.w;
    return v;
}

// chunk-buffer address with T2 XOR swizzle: 16B-slot index ^ (row&7)
__device__ __forceinline__ int chadr(int r, int c8) {   // c8 in bf16 elems, mult of 8
    return r * CH_S + (c8 ^ ((r & 7) << 3));
}

// ---- weight fp32 -> bf16 pre-convert ----
__global__ void conv_weights(const float* __restrict__ W1,
                             const float* __restrict__ W2,
                             __bf16* __restrict__ ws) {
    const int n1 = (H1N * OBS) / 8;     // 25600
    const int n2 = (H2N * H1N) / 8;     // 15000
    int i = blockIdx.x * blockDim.x + threadIdx.x;
    if (i < n1) {
        const float4* p = reinterpret_cast<const float4*>(W1 + (size_t)i * 8);
        *reinterpret_cast<bf16x8*>(ws + (size_t)i * 8) = cvt8(p[0], p[1]);
    } else if (i < n1 + n2) {
        int j = i - n1;
        const float4* p = reinterpret_cast<const float4*>(W2 + (size_t)j * 8);
        *reinterpret_cast<bf16x8*>(ws + (size_t)(H1N * OBS) + (size_t)j * 8) =
            cvt8(p[0], p[1]);
    }
}

template <bool WBF16>
__global__ __launch_bounds__(NTH, 4) void autoprune_mfma(
    const float* __restrict__ frame, const float* __restrict__ reward,
    const int*   __restrict__ last_action, const float* __restrict__ eps,
    const float* __restrict__ W1f, const float* __restrict__ b1,
    const float* __restrict__ W2f, const float* __restrict__ b2,
    const float* __restrict__ Wp, const float* __restrict__ bp,
    const float* __restrict__ Wb, const float* __restrict__ bb,
    const __bf16* __restrict__ W1b, const __bf16* __restrict__ W2b,
    float* __restrict__ out)
{
    __shared__ __bf16 sm_chunk[2][BM * CH_S];   // 32,768 B (frame dbuf, swizzled)
    __shared__ __bf16 sm_h1[BM * H1_S];         // 108,544 B  => 141,312 total

    const int tid  = threadIdx.x;
    const int w    = tid >> 6;          // wave 0..15
    const int wm   = w & 3;             // M quarter: rows wm*32
    const int wc   = w >> 2;            // N quarter
    const int l15  = tid & 15;
    const int lg   = (tid & 63) >> 4;
    const int row0 = blockIdx.x * BM;

    // staging coords: thread -> (row sr, 8-col group sc); 8 threads per row
    const int sr = tid >> 3;            // 0..127
    const int sc = (tid & 7) * 8;       // 0..56
    const float* fbase = frame + (size_t)(row0 + sr) * OBS + sc;

    // ---------------- Prologue: stage chunk 0 (swizzled write) ----------------
    {
        float4 a = *reinterpret_cast<const float4*>(fbase);
        float4 b = *reinterpret_cast<const float4*>(fbase + 4);
        *reinterpret_cast<bf16x8*>(&sm_chunk[0][chadr(sr, sc)]) = cvt8(a, b);
    }
    __syncthreads();

    // ---------------- Layer 1: h1 = relu(frame @ W1^T + b1) -------------------
    // M=128 (wave: 2 mt of its quarter), N=400 (25 nt: wave-col wc + 4*ti),
    // K=512 = 8 chunks x 2 ksteps. Chunk-dbuf + early-issue (T14).
    {
        f32x4 acc[7][2];
        #pragma unroll
        for (int a = 0; a < 7; ++a)
            #pragma unroll
            for (int b = 0; b < 2; ++b) acc[a][b] = (f32x4){0.f, 0.f, 0.f, 0.f};

        for (int c = 0; c < NCHUNK; ++c) {
            float4 pa, pb;
            if (c < NCHUNK - 1) {       // issue next-chunk loads before compute
                pa = *reinterpret_cast<const float4*>(fbase + (c + 1) * CH_K);
                pb = *reinterpret_cast<const float4*>(fbase + (c + 1) * CH_K + 4);
            }
            const __bf16* buf = sm_chunk[c & 1];
            #pragma unroll
            for (int ks = 0; ks < 2; ++ks) {
                const int kl = ks * 32 + lg * 8;
                bf16x8 afr[2];
                #pragma unroll
                for (int mt = 0; mt < 2; ++mt) {
                    int r = wm * 32 + mt * 16 + l15;
                    afr[mt] = *reinterpret_cast<const bf16x8*>(&buf[chadr(r, kl)]);
                }
                const int kg = c * CH_K + kl;
                #pragma unroll
                for (int ti = 0; ti < 7; ++ti) {
                    int nt = wc + ti * 4;
                    if (nt < 25) {                  // wave-uniform guard
                        bf16x8 bfr;
                        if constexpr (WBF16) {
                            bfr = *reinterpret_cast<const bf16x8*>(
                                W1b + (size_t)(nt * 16 + l15) * OBS + kg);
                        } else {
                            const float4* wp = reinterpret_cast<const float4*>(
                                W1f + (size_t)(nt * 16 + l15) * OBS + kg);
                            bfr = cvt8(wp[0], wp[1]);
                        }
                        #pragma unroll
                        for (int mt = 0; mt < 2; ++mt)
                            acc[ti][mt] = __builtin_amdgcn_mfma_f32_16x16x32_bf16(
                                afr[mt], bfr, acc[ti][mt], 0, 0, 0);
                    }
                }
            }
            if (c < NCHUNK - 1)
                *reinterpret_cast<bf16x8*>(
                    &sm_chunk[(c + 1) & 1][chadr(sr, sc)]) = cvt8(pa, pb);
            __syncthreads();
        }

        // C-store: col = nt*16 + l15, row = wm*32 + mt*16 + lg*4 + j
        #pragma unroll
        for (int ti = 0; ti < 7; ++ti) {
            int nt = wc + ti * 4;
            if (nt < 25) {
                int c = nt * 16 + l15;
                float bias = b1[c];
                #pragma unroll
                for (int mt = 0; mt < 2; ++mt)
                    #pragma unroll
                    for (int j = 0; j < 4; ++j) {
                        int r = wm * 32 + mt * 16 + lg * 4 + j;
                        sm_h1[r * H1_S + c] =
                            (__bf16)fmaxf(acc[ti][mt][j] + bias, 0.0f);
                    }
            }
        }
        // zero h1 K-pad cols 400..423 (128 rows x 3 groups)
        if (tid < 384) {
            int r = tid / 3, cz = 400 + (tid % 3) * 8;
            bf16x8 z;
            #pragma unroll
            for (int j = 0; j < 8; ++j) z[j] = (__bf16)0.0f;
            *reinterpret_cast<bf16x8*>(&sm_h1[r * H1_S + cz]) = z;
        }
    }
    __syncthreads();

    // ---------------- Layer 2: h2 = relu(h1 @ W2^T + b2) ----------------------
    // M=128, N=304 (19 nt: wc + 4*ti), K=416 (13 ksteps, no barriers)
    f32x4 acc2[5][2];
    #pragma unroll
    for (int a = 0; a < 5; ++a)
        #pragma unroll
        for (int b = 0; b < 2; ++b) acc2[a][b] = (f32x4){0.f, 0.f, 0.f, 0.f};

    #pragma unroll 2
    for (int ks = 0; ks < 13; ++ks) {
        const int kb = ks * 32 + lg * 8;
        bf16x8 afr[2];
        #pragma unroll
        for (int mt = 0; mt < 2; ++mt) {
            int r = wm * 32 + mt * 16 + l15;
            afr[mt] = *reinterpret_cast<const bf16x8*>(&sm_h1[r * H1_S + kb]);
        }
        const int kbw = (kb >= 400) ? 0 : kb;    // A is zero there; clamp B addr
        #pragma unroll
        for (int ti = 0; ti < 5; ++ti) {
            int nt = wc + ti * 4;
            if (nt < 19) {
                int cc = nt * 16 + l15;
                if (cc >= 300) cc = 299;         // results discarded
                bf16x8 bfr;
                if constexpr (WBF16) {
                    bfr = *reinterpret_cast<const bf16x8*>(
                        W2b + (size_t)cc * H1N + kbw);
                } else {
                    const float4* wp = reinterpret_cast<const float4*>(
                        W2f + (size_t)cc * H1N + kbw);
                    bfr = cvt8(wp[0], wp[1]);
                }
                #pragma unroll
                for (int mt = 0; mt < 2; ++mt)
                    acc2[ti][mt] = __builtin_amdgcn_mfma_f32_16x16x32_bf16(
                        afr[mt], bfr, acc2[ti][mt], 0, 0, 0);
            }
        }
    }
    __syncthreads();   // all h1 reads done; safe to overwrite in place

    // core (in place): cols 0..299 = relu(h2), 300=cr, 301=la, 302..319=0
    #pragma unroll
    for (int ti = 0; ti < 5; ++ti) {
        int nt = wc + ti * 4;
        if (nt < 19) {
            int c = nt * 16 + l15;
            if (c < 300) {
                float bias = b2[c];
                #pragma unroll
                for (int mt = 0; mt < 2; ++mt)
                    #pragma unroll
                    for (int j = 0; j < 4; ++j) {
                        int r = wm * 32 + mt * 16 + lg * 4 + j;
                        sm_h1[r * H1_S + c] =
                            (__bf16)fmaxf(acc2[ti][mt][j] + bias, 0.0f);
                    }
            }
        }
    }
    if (tid < BM) {
        int r = row0 + tid;
        float cr = fminf(fmaxf(reward[r], -1.0f), 1.0f);
        bf16x4 tail;
        tail[0] = (__bf16)cr;
        tail[1] = (__bf16)(float)last_action[r];
        tail[2] = (__bf16)0.0f;
        tail[3] = (__bf16)0.0f;
        *reinterpret_cast<bf16x4*>(&sm_h1[tid * H1_S + 300]) = tail;
        bf16x8 z;
        #pragma unroll
        for (int j = 0; j < 8; ++j) z[j] = (__bf16)0.0f;
        *reinterpret_cast<bf16x8*>(&sm_h1[tid * H1_S + 304]) = z;
        *reinterpret_cast<bf16x8*>(&sm_h1[tid * H1_S + 312]) = z;
    }
    __syncthreads();

    // ---------------- Head: MFMA with register-built B ------------------------
    // waves 0..7 handle 16 rows each; lane l15 = output o (0:mu, 1:sigma, 2:bl)
    if (w < 8) {
        f32x4 hac = (f32x4){0.f, 0.f, 0.f, 0.f};
        const float* wsrc = (l15 == 2) ? Wb : (Wp + l15 * CORE);  // l15>2 unused
        #pragma unroll
        for (int ks = 0; ks < 10; ++ks) {
            int kb = ks * 32 + lg * 8;
            bf16x8 afr = *reinterpret_cast<const bf16x8*>(
                &sm_h1[(w * 16 + l15) * H1_S + kb]);
            bf16x8 bfr;
            #pragma unroll
            for (int e = 0; e < 8; ++e) {
                int k = kb + e;
                bfr[e] = (l15 < 3 && k < CORE) ? (__bf16)wsrc[k] : (__bf16)0.0f;
            }
            hac = __builtin_amdgcn_mfma_f32_16x16x32_bf16(afr, bfr, hac, 0, 0, 0);
        }
        float bias = (l15 == 0) ? bp[0] : (l15 == 1) ? bp[1] : (l15 == 2) ? bb[0] : 0.0f;
        #pragma unroll
        for (int j = 0; j < 4; ++j) {
            float v = hac[j] + bias;
            if (l15 < 2) v = 1.0f / (1.0f + __expf(-v));
            float ot = __shfl_xor(v, 1);       // lane l15=0 receives sigma
            int r = row0 + w * 16 + lg * 4 + j;
            if (l15 == 0) {
                out[(size_t)r * 4 + 0] = v;                     // mu
                out[(size_t)r * 4 + 3] = fmaf(ot, eps[r], v);   // action
            } else if (l15 == 1) {
                out[(size_t)r * 4 + 1] = v;                     // sigma
            } else if (l15 == 2) {
                out[(size_t)r * 4 + 2] = v;                     // baseline
            }
        }
    }
}

extern "C" void kernel_launch(void* const* d_in, const int* in_sizes, int n_in,
                              void* d_out, int out_size, void* d_ws, size_t ws_size,
                              hipStream_t stream) {
    const float* frame       = (const float*)d_in[0];
    const float* reward      = (const float*)d_in[1];
    const int*   last_action = (const int*)  d_in[2];
    const float* eps         = (const float*)d_in[3];
    const float* W1          = (const float*)d_in[4];
    const float* b1          = (const float*)d_in[5];
    const float* W2          = (const float*)d_in[6];
    const float* b2          = (const float*)d_in[7];
    const float* Wp          = (const float*)d_in[8];
    const float* bp          = (const float*)d_in[9];
    const float* Wb          = (const float*)d_in[10];
    const float* bb          = (const float*)d_in[11];
    float* out = (float*)d_out;

    const size_t wbytes = (size_t)(H1N * OBS + H2N * H1N) * 2;   // 649600
    dim3 grid(TBR / BM);   // 1024 blocks, 1024 threads, 1 block/CU (141 KB LDS)

    if (ws_size >= wbytes) {
        __bf16* wsb = (__bf16*)d_ws;
        int nconv = (H1N * OBS + H2N * H1N) / 8;                 // 40600
        conv_weights<<<(nconv + 255) / 256, 256, 0, stream>>>(W1, W2, wsb);
        autoprune_mfma<true><<<grid, NTH, 0, stream>>>(
            frame, reward, last_action, eps, W1, b1, W2, b2, Wp, bp, Wb, bb,
            (const __bf16*)wsb, (const __bf16*)(wsb + H1N * OBS), out);
    } else {
        autoprune_mfma<false><<<grid, NTH, 0, stream>>>(
            frame, reward, last_action, eps, W1, b1, W2, b2, Wp, bp, Wb, bb,
            (const __bf16*)nullptr, (const __bf16*)nullptr, out);
    }
}

// Round 7
// 294.406 us; speedup vs baseline: 1.0776x; 1.0776x over previous
//
#include <hip/hip_runtime.h>
#include <math.h>

// Problem constants
#define TBR  131072      // 64*2048 rows
#define OBS  512
#define H1N  400
#define H2N  300
#define CORE 302

// Geometry (r3 champion): 64 rows/block, 512 threads, 2 blocks/CU.
#define CH_K   64        // frame K-chunk
#define NCHUNK 8         // OBS / CH_K
#define CH_S   64        // chunk stride, exact; T2 XOR-swizzled
#define H1_S   424       // h1/core stride (K padded 400->416, head pad ->320)

typedef __bf16 bf16x8 __attribute__((ext_vector_type(8)));
typedef __bf16 bf16x4 __attribute__((ext_vector_type(4)));
typedef float  f32x4  __attribute__((ext_vector_type(4)));

__device__ __forceinline__ bf16x8 cvt8(float4 a, float4 b) {
    bf16x8 v;
    v[0] = (__bf16)a.x; v[1] = (__bf16)a.y; v[2] = (__bf16)a.z; v[3] = (__bf16)a.w;
    v[4] = (__bf16)b.x; v[5] = (__bf16)b.y; v[6] = (__bf16)b.z; v[7] = (__bf16)b.w;
    return v;
}

// chunk-buffer address, T2 XOR swizzle on 16B slots (write & read use SAME map)
__device__ __forceinline__ int chadr(int r, int c8) {
    return r * CH_S + (c8 ^ ((r & 7) << 3));
}

// ---- weight fp32 -> bf16 pre-convert ----
__global__ void conv_weights(const float* __restrict__ W1,
                             const float* __restrict__ W2,
                             __bf16* __restrict__ ws) {
    const int n1 = (H1N * OBS) / 8;     // 25600
    const int n2 = (H2N * H1N) / 8;     // 15000
    int i = blockIdx.x * blockDim.x + threadIdx.x;
    if (i < n1) {
        const float4* p = reinterpret_cast<const float4*>(W1 + (size_t)i * 8);
        *reinterpret_cast<bf16x8*>(ws + (size_t)i * 8) = cvt8(p[0], p[1]);
    } else if (i < n1 + n2) {
        int j = i - n1;
        const float4* p = reinterpret_cast<const float4*>(W2 + (size_t)j * 8);
        *reinterpret_cast<bf16x8*>(ws + (size_t)(H1N * OBS) + (size_t)j * 8) =
            cvt8(p[0], p[1]);
    }
}

template <bool WBF16>
__global__ __launch_bounds__(512, 4) void autoprune_mfma(
    const float* __restrict__ frame, const float* __restrict__ reward,
    const int*   __restrict__ last_action, const float* __restrict__ eps,
    const float* __restrict__ W1f, const float* __restrict__ b1,
    const float* __restrict__ W2f, const float* __restrict__ b2,
    const float* __restrict__ Wp, const float* __restrict__ bp,
    const float* __restrict__ Wb, const float* __restrict__ bb,
    const __bf16* __restrict__ W1b, const __bf16* __restrict__ W2b,
    float* __restrict__ out)
{
    __shared__ __bf16 sm_chunk[2][64 * CH_S];   // 16,384 B (swizzled dbuf)
    __shared__ __bf16 sm_h1[64 * H1_S];         // 54,272 B  => 70,656 total

    const int tid  = threadIdx.x;
    const int w    = tid >> 6;
    const int l15  = tid & 15;
    const int lg   = (tid & 63) >> 4;
    const int row0 = blockIdx.x * 64;

    // staging coords: 8 threads/row
    const int sr = tid >> 3;            // 0..63
    const int sc = (tid & 7) * 8;       // 0..56
    const float* fbase = frame + (size_t)(row0 + sr) * OBS + sc;

    // B-fragment loader for W1 (one kstep: 4 n-tiles for this wave)
    auto loadB1 = [&](int kg, bf16x8* dst) {
        #pragma unroll
        for (int ti = 0; ti < 4; ++ti) {
            int nt = w + ti * 8;
            if (nt < 25) {                      // wave-uniform
                if constexpr (WBF16) {
                    dst[ti] = *reinterpret_cast<const bf16x8*>(
                        W1b + (size_t)(nt * 16 + l15) * OBS + kg);
                } else {
                    const float4* wp = reinterpret_cast<const float4*>(
                        W1f + (size_t)(nt * 16 + l15) * OBS + kg);
                    dst[ti] = cvt8(wp[0], wp[1]);
                }
            }
        }
    };

    // ---------------- Prologue ------------------------------------------------
    bf16x8 bpre[4];                     // B pipeline register (1 kstep ahead)
    {
        float4 a = *reinterpret_cast<const float4*>(fbase);
        float4 b = *reinterpret_cast<const float4*>(fbase + 4);
        loadB1(lg * 8, bpre);           // chunk0/ks0 B — in flight across barrier
        // zero h1 K-pad cols 400..423
        if (tid < 192) {
            int r = tid / 3, c = 400 + (tid % 3) * 8;
            bf16x8 z;
            #pragma unroll
            for (int j = 0; j < 8; ++j) z[j] = (__bf16)0.0f;
            *reinterpret_cast<bf16x8*>(&sm_h1[r * H1_S + c]) = z;
        }
        *reinterpret_cast<bf16x8*>(&sm_chunk[0][chadr(sr, sc)]) = cvt8(a, b);
    }
    asm volatile("s_waitcnt lgkmcnt(0)" ::: "memory");
    __builtin_amdgcn_s_barrier();

    // ---------------- Layer 1: h1 = relu(frame @ W1^T + b1) -------------------
    // M=64 (4 mt), N=400 (25 nt over 8 waves), K=512 = 8 chunks x 2 ksteps.
    // Raw barriers (lgkm-only): B-loads stay in flight across chunk boundaries.
    {
        f32x4 acc[4][4];
        #pragma unroll
        for (int a = 0; a < 4; ++a)
            #pragma unroll
            for (int b = 0; b < 4; ++b) acc[a][b] = (f32x4){0.f, 0.f, 0.f, 0.f};

        #pragma unroll
        for (int c = 0; c < NCHUNK; ++c) {
            float4 pa, pb;
            if (c < NCHUNK - 1) {       // next-chunk frame loads, oldest in queue
                pa = *reinterpret_cast<const float4*>(fbase + (c + 1) * CH_K);
                pb = *reinterpret_cast<const float4*>(fbase + (c + 1) * CH_K + 4);
            }
            const __bf16* buf = sm_chunk[c & 1];

            // ---- ks = 0 (B from bpre); prefetch ks=1 B ----
            bf16x8 bnxt[4];
            loadB1(c * CH_K + 32 + lg * 8, bnxt);
            {
                const int kl = lg * 8;
                #pragma unroll
                for (int mt = 0; mt < 4; ++mt) {
                    bf16x8 afr = *reinterpret_cast<const bf16x8*>(
                        &buf[chadr(mt * 16 + l15, kl)]);
                    #pragma unroll
                    for (int ti = 0; ti < 4; ++ti)
                        if (w + ti * 8 < 25)
                            acc[ti][mt] = __builtin_amdgcn_mfma_f32_16x16x32_bf16(
                                afr, bpre[ti], acc[ti][mt], 0, 0, 0);
                }
            }
            // ---- prefetch next chunk's ks=0 B BEFORE the barrier ----
            if (c < NCHUNK - 1) loadB1((c + 1) * CH_K + lg * 8, bpre);
            // ---- ks = 1 (B from bnxt) ----
            {
                const int kl = 32 + lg * 8;
                #pragma unroll
                for (int mt = 0; mt < 4; ++mt) {
                    bf16x8 afr = *reinterpret_cast<const bf16x8*>(
                        &buf[chadr(mt * 16 + l15, kl)]);
                    #pragma unroll
                    for (int ti = 0; ti < 4; ++ti)
                        if (w + ti * 8 < 25)
                            acc[ti][mt] = __builtin_amdgcn_mfma_f32_16x16x32_bf16(
                                afr, bnxt[ti], acc[ti][mt], 0, 0, 0);
                }
            }
            if (c < NCHUNK - 1) {
                *reinterpret_cast<bf16x8*>(
                    &sm_chunk[(c + 1) & 1][chadr(sr, sc)]) = cvt8(pa, pb);
                asm volatile("s_waitcnt lgkmcnt(0)" ::: "memory");
                __builtin_amdgcn_s_barrier();
            }
        }

        // C-store: col = nt*16 + l15, row = mt*16 + lg*4 + j
        #pragma unroll
        for (int ti = 0; ti < 4; ++ti) {
            int nt = w + ti * 8;
            if (nt < 25) {
                int c = nt * 16 + l15;
                float bias = b1[c];
                #pragma unroll
                for (int mt = 0; mt < 4; ++mt)
                    #pragma unroll
                    for (int j = 0; j < 4; ++j) {
                        int r = mt * 16 + lg * 4 + j;
                        sm_h1[r * H1_S + c] =
                            (__bf16)fmaxf(acc[ti][mt][j] + bias, 0.0f);
                    }
            }
        }
    }
    __syncthreads();

    // ---------------- Layer 2: h2 = relu(h1 @ W2^T + b2) ----------------------
    // M=64, N=304 (19 nt), K=416 (13 ksteps, no barriers; A zero-padded)
    f32x4 acc2[3][4];
    #pragma unroll
    for (int a = 0; a < 3; ++a)
        #pragma unroll
        for (int b = 0; b < 4; ++b) acc2[a][b] = (f32x4){0.f, 0.f, 0.f, 0.f};

    #pragma unroll 2
    for (int ks = 0; ks < 13; ++ks) {
        const int kb = ks * 32 + lg * 8;
        bf16x8 afr[4];
        #pragma unroll
        for (int mt = 0; mt < 4; ++mt)
            afr[mt] = *reinterpret_cast<const bf16x8*>(
                &sm_h1[(mt * 16 + l15) * H1_S + kb]);
        const int kbw = (kb >= 400) ? 0 : kb;    // A is zero there; clamp B addr
        #pragma unroll
        for (int ti = 0; ti < 3; ++ti) {
            int nt = w + ti * 8;
            if (nt < 19) {
                int cc = nt * 16 + l15;
                if (cc >= 300) cc = 299;         // results discarded
                bf16x8 bfr;
                if constexpr (WBF16) {
                    bfr = *reinterpret_cast<const bf16x8*>(
                        W2b + (size_t)cc * H1N + kbw);
                } else {
                    const float4* wp = reinterpret_cast<const float4*>(
                        W2f + (size_t)cc * H1N + kbw);
                    bfr = cvt8(wp[0], wp[1]);
                }
                #pragma unroll
                for (int mt = 0; mt < 4; ++mt)
                    acc2[ti][mt] = __builtin_amdgcn_mfma_f32_16x16x32_bf16(
                        afr[mt], bfr, acc2[ti][mt], 0, 0, 0);
            }
        }
    }
    __syncthreads();   // all h1 reads done; safe to overwrite in place

    // core (in place): cols 0..299 = relu(h2), 300=cr, 301=la, 302..319=0
    #pragma unroll
    for (int ti = 0; ti < 3; ++ti) {
        int nt = w + ti * 8;
        if (nt < 19) {
            int c = nt * 16 + l15;
            if (c < 300) {
                float bias = b2[c];
                #pragma unroll
                for (int mt = 0; mt < 4; ++mt)
                    #pragma unroll
                    for (int j = 0; j < 4; ++j) {
                        int r = mt * 16 + lg * 4 + j;
                        sm_h1[r * H1_S + c] =
                            (__bf16)fmaxf(acc2[ti][mt][j] + bias, 0.0f);
                    }
            }
        }
    }
    if (tid < 64) {
        int r = row0 + tid;
        float cr = fminf(fmaxf(reward[r], -1.0f), 1.0f);
        bf16x4 tail;
        tail[0] = (__bf16)cr;
        tail[1] = (__bf16)(float)last_action[r];
        tail[2] = (__bf16)0.0f;
        tail[3] = (__bf16)0.0f;
        *reinterpret_cast<bf16x4*>(&sm_h1[tid * H1_S + 300]) = tail;
        bf16x8 z;
        #pragma unroll
        for (int j = 0; j < 8; ++j) z[j] = (__bf16)0.0f;
        *reinterpret_cast<bf16x8*>(&sm_h1[tid * H1_S + 304]) = z;
        *reinterpret_cast<bf16x8*>(&sm_h1[tid * H1_S + 312]) = z;
    }
    __syncthreads();

    // ---------------- Head: MFMA with register-built B ------------------------
    // waves 0..3 handle 16 rows each; lane l15 = output o (0:mu, 1:sigma, 2:bl)
    if (w < 4) {
        f32x4 hac = (f32x4){0.f, 0.f, 0.f, 0.f};
        const float* wsrc = (l15 == 2) ? Wb : (Wp + l15 * CORE);  // l15>2 unused
        #pragma unroll
        for (int ks = 0; ks < 10; ++ks) {
            int kb = ks * 32 + lg * 8;
            bf16x8 afr = *reinterpret_cast<const bf16x8*>(
                &sm_h1[(w * 16 + l15) * H1_S + kb]);
            bf16x8 bfr;
            #pragma unroll
            for (int e = 0; e < 8; ++e) {
                int k = kb + e;
                bfr[e] = (l15 < 3 && k < CORE) ? (__bf16)wsrc[k] : (__bf16)0.0f;
            }
            hac = __builtin_amdgcn_mfma_f32_16x16x32_bf16(afr, bfr, hac, 0, 0, 0);
        }
        float bias = (l15 == 0) ? bp[0] : (l15 == 1) ? bp[1] : (l15 == 2) ? bb[0] : 0.0f;
        #pragma unroll
        for (int j = 0; j < 4; ++j) {
            float v = hac[j] + bias;
            if (l15 < 2) v = 1.0f / (1.0f + __expf(-v));
            float ot = __shfl_xor(v, 1);       // lane l15=0 receives sigma
            int r = row0 + w * 16 + lg * 4 + j;
            if (l15 == 0) {
                out[(size_t)r * 4 + 0] = v;                     // mu
                out[(size_t)r * 4 + 3] = fmaf(ot, eps[r], v);   // action
            } else if (l15 == 1) {
                out[(size_t)r * 4 + 1] = v;                     // sigma
            } else if (l15 == 2) {
                out[(size_t)r * 4 + 2] = v;                     // baseline
            }
        }
    }
}

extern "C" void kernel_launch(void* const* d_in, const int* in_sizes, int n_in,
                              void* d_out, int out_size, void* d_ws, size_t ws_size,
                              hipStream_t stream) {
    const float* frame       = (const float*)d_in[0];
    const float* reward      = (const float*)d_in[1];
    const int*   last_action = (const int*)  d_in[2];
    const float* eps         = (const float*)d_in[3];
    const float* W1          = (const float*)d_in[4];
    const float* b1          = (const float*)d_in[5];
    const float* W2          = (const float*)d_in[6];
    const float* b2          = (const float*)d_in[7];
    const float* Wp          = (const float*)d_in[8];
    const float* bp          = (const float*)d_in[9];
    const float* Wb          = (const float*)d_in[10];
    const float* bb          = (const float*)d_in[11];
    float* out = (float*)d_out;

    const size_t wbytes = (size_t)(H1N * OBS + H2N * H1N) * 2;   // 649600
    dim3 grid(TBR / 64);   // 2048 blocks, 512 threads, 2 blocks/CU (70.7 KB LDS)

    if (ws_size >= wbytes) {
        __bf16* wsb = (__bf16*)d_ws;
        int nconv = (H1N * OBS + H2N * H1N) / 8;                 // 40600
        conv_weights<<<(nconv + 255) / 256, 256, 0, stream>>>(W1, W2, wsb);
        autoprune_mfma<true><<<grid, 512, 0, stream>>>(
            frame, reward, last_action, eps, W1, b1, W2, b2, Wp, bp, Wb, bb,
            (const __bf16*)wsb, (const __bf16*)(wsb + H1N * OBS), out);
    } else {
        autoprune_mfma<false><<<grid, 512, 0, stream>>>(
            frame, reward, last_action, eps, W1, b1, W2, b2, Wp, bp, Wb, bb,
            (const __bf16*)nullptr, (const __bf16*)nullptr, out);
    }
}

// Round 8
// 261.076 us; speedup vs baseline: 1.2151x; 1.1277x over previous
//
#include <hip/hip_runtime.h>
#include <math.h>

// Problem constants
#define TBR  131072      // 64*2048 rows
#define OBS  512
#define H1N  400
#define H2N  300
#define CORE 302

// Shared tiling
#define CH_K   64        // K-chunk
#define CH_S   64        // chunk stride (exact, T2 XOR-swizzled)
#define H1G_S  448       // h1 global row stride (400 padded to 7*64)
#define CO_S   328       // core LDS stride (302 padded to 320 for head)
// fused fallback (exact r3)
#define NCHUNK 8
#define FCH_S  72
#define H1_S   424

typedef __bf16 bf16x8 __attribute__((ext_vector_type(8)));
typedef __bf16 bf16x4 __attribute__((ext_vector_type(4)));
typedef float  f32x4  __attribute__((ext_vector_type(4)));

__device__ __forceinline__ bf16x8 cvt8(float4 a, float4 b) {
    bf16x8 v;
    v[0] = (__bf16)a.x; v[1] = (__bf16)a.y; v[2] = (__bf16)a.z; v[3] = (__bf16)a.w;
    v[4] = (__bf16)b.x; v[5] = (__bf16)b.y; v[6] = (__bf16)b.z; v[7] = (__bf16)b.w;
    return v;
}

// chunk-buffer address, T2 XOR swizzle on 16B slots (write & read same map)
__device__ __forceinline__ int chadr(int r, int c8) {
    return r * CH_S + (c8 ^ ((r & 7) << 3));
}

// ---- weight fp32 -> bf16 pre-convert ----
__global__ void conv_weights(const float* __restrict__ W1,
                             const float* __restrict__ W2,
                             __bf16* __restrict__ ws) {
    const int n1 = (H1N * OBS) / 8;     // 25600
    const int n2 = (H2N * H1N) / 8;     // 15000
    int i = blockIdx.x * blockDim.x + threadIdx.x;
    if (i < n1) {
        const float4* p = reinterpret_cast<const float4*>(W1 + (size_t)i * 8);
        *reinterpret_cast<bf16x8*>(ws + (size_t)i * 8) = cvt8(p[0], p[1]);
    } else if (i < n1 + n2) {
        int j = i - n1;
        const float4* p = reinterpret_cast<const float4*>(W2 + (size_t)j * 8);
        *reinterpret_cast<bf16x8*>(ws + (size_t)(H1N * OBS) + (size_t)j * 8) =
            cvt8(p[0], p[1]);
    }
}

// ================= GEMM1: h1 = relu(frame @ W1^T + b1) -> d_ws ==============
// M=64/block, 512 thr, LDS = 16 KB swizzled frame chunks only. 2048 blocks.
__global__ __launch_bounds__(512, 4) void gemm1(
    const float* __restrict__ frame, const __bf16* __restrict__ W1b,
    const float* __restrict__ b1, __bf16* __restrict__ h1g)
{
    __shared__ __bf16 smc[2][64 * CH_S];   // 16,384 B

    const int tid  = threadIdx.x;
    const int w    = tid >> 6;
    const int l15  = tid & 15;
    const int lg   = (tid & 63) >> 4;
    const int row0 = blockIdx.x * 64;

    const int sr = tid >> 3;               // staging: 8 threads/row
    const int sc = (tid & 7) * 8;
    const float* fbase = frame + (size_t)(row0 + sr) * OBS + sc;

    // prologue: stage chunk 0
    {
        float4 a = *reinterpret_cast<const float4*>(fbase);
        float4 b = *reinterpret_cast<const float4*>(fbase + 4);
        *reinterpret_cast<bf16x8*>(&smc[0][chadr(sr, sc)]) = cvt8(a, b);
    }
    __syncthreads();

    f32x4 acc[4][4];
    #pragma unroll
    for (int a = 0; a < 4; ++a)
        #pragma unroll
        for (int b = 0; b < 4; ++b) acc[a][b] = (f32x4){0.f, 0.f, 0.f, 0.f};

    for (int c = 0; c < NCHUNK; ++c) {
        float4 pa, pb;
        if (c < NCHUNK - 1) {              // issue next-chunk loads early (T14)
            pa = *reinterpret_cast<const float4*>(fbase + (c + 1) * CH_K);
            pb = *reinterpret_cast<const float4*>(fbase + (c + 1) * CH_K + 4);
        }
        const __bf16* buf = smc[c & 1];
        #pragma unroll
        for (int ks = 0; ks < 2; ++ks) {
            const int kl = ks * 32 + lg * 8;
            bf16x8 afr[4];
            #pragma unroll
            for (int mt = 0; mt < 4; ++mt)
                afr[mt] = *reinterpret_cast<const bf16x8*>(
                    &buf[chadr(mt * 16 + l15, kl)]);
            const int kg = c * CH_K + kl;
            #pragma unroll
            for (int ti = 0; ti < 4; ++ti) {
                int nt = w + ti * 8;
                if (nt < 25) {             // wave-uniform guard
                    bf16x8 bfr = *reinterpret_cast<const bf16x8*>(
                        W1b + (size_t)(nt * 16 + l15) * OBS + kg);
                    #pragma unroll
                    for (int mt = 0; mt < 4; ++mt)
                        acc[ti][mt] = __builtin_amdgcn_mfma_f32_16x16x32_bf16(
                            afr[mt], bfr, acc[ti][mt], 0, 0, 0);
                }
            }
        }
        if (c < NCHUNK - 1)
            *reinterpret_cast<bf16x8*>(
                &smc[(c + 1) & 1][chadr(sr, sc)]) = cvt8(pa, pb);
        __syncthreads();
    }

    // C-store direct to global h1 (bf16): col = nt*16+l15, row = mt*16+lg*4+j
    #pragma unroll
    for (int ti = 0; ti < 4; ++ti) {
        int nt = w + ti * 8;
        if (nt < 25) {
            int c = nt * 16 + l15;
            float bias = b1[c];
            #pragma unroll
            for (int mt = 0; mt < 4; ++mt)
                #pragma unroll
                for (int j = 0; j < 4; ++j) {
                    int r = mt * 16 + lg * 4 + j;
                    h1g[(size_t)(row0 + r) * H1G_S + c] =
                        (__bf16)fmaxf(acc[ti][mt][j] + bias, 0.0f);
                }
        }
    }
    // zero K-pad cols 400..447 (64 rows x 48 cols, bf16x4 groups)
    for (int p = tid; p < 768; p += 512) {
        int r = p / 12, g = p - r * 12;
        bf16x4 z; z[0] = z[1] = z[2] = z[3] = (__bf16)0.0f;
        *reinterpret_cast<bf16x4*>(
            &h1g[(size_t)(row0 + r) * H1G_S + 400 + g * 4]) = z;
    }
}

// ============ GEMM2+head: core=[relu(h1@W2^T+b2)|cr|la]; outputs =============
// M=64/block, 512 thr, LDS = 16 KB h1 chunks + 42 KB core. 2048 blocks.
__global__ __launch_bounds__(512, 4) void gemm2_head(
    const __bf16* __restrict__ h1g, const __bf16* __restrict__ W2b,
    const float* __restrict__ b2,
    const float* __restrict__ reward, const int* __restrict__ last_action,
    const float* __restrict__ eps,
    const float* __restrict__ Wp, const float* __restrict__ bp,
    const float* __restrict__ Wb, const float* __restrict__ bb,
    float* __restrict__ out)
{
    __shared__ __bf16 smc[2][64 * CH_S];   // 16,384 B (h1 chunks, swizzled)
    __shared__ __bf16 smo[64 * CO_S];      // 41,984 B core   => 58.4 KB total

    const int tid  = threadIdx.x;
    const int w    = tid >> 6;
    const int l15  = tid & 15;
    const int lg   = (tid & 63) >> 4;
    const int row0 = blockIdx.x * 64;

    const int sr = tid >> 3;
    const int sc = (tid & 7) * 8;
    const __bf16* hbase = h1g + (size_t)(row0 + sr) * H1G_S + sc;

    // prologue: stage chunk 0 (bf16 direct, 16B/lane)
    *reinterpret_cast<bf16x8*>(&smc[0][chadr(sr, sc)]) =
        *reinterpret_cast<const bf16x8*>(hbase);
    __syncthreads();

    f32x4 acc2[3][4];
    #pragma unroll
    for (int a = 0; a < 3; ++a)
        #pragma unroll
        for (int b = 0; b < 4; ++b) acc2[a][b] = (f32x4){0.f, 0.f, 0.f, 0.f};

    const int NCH2 = H1G_S / CH_K;         // 7 chunks over padded K=448
    for (int c = 0; c < NCH2; ++c) {
        bf16x8 pre;
        if (c < NCH2 - 1)
            pre = *reinterpret_cast<const bf16x8*>(hbase + (c + 1) * CH_K);
        const __bf16* buf = smc[c & 1];
        #pragma unroll
        for (int ks = 0; ks < 2; ++ks) {
            const int kl = ks * 32 + lg * 8;
            bf16x8 afr[4];
            #pragma unroll
            for (int mt = 0; mt < 4; ++mt)
                afr[mt] = *reinterpret_cast<const bf16x8*>(
                    &buf[chadr(mt * 16 + l15, kl)]);
            const int kg  = c * CH_K + kl;
            const int kbw = (kg >= 400) ? 0 : kg;   // A is zero there
            #pragma unroll
            for (int ti = 0; ti < 3; ++ti) {
                int nt = w + ti * 8;
                if (nt < 19) {
                    int cc = nt * 16 + l15;
                    if (cc >= 300) cc = 299;        // results discarded
                    bf16x8 bfr = *reinterpret_cast<const bf16x8*>(
                        W2b + (size_t)cc * H1N + kbw);
                    #pragma unroll
                    for (int mt = 0; mt < 4; ++mt)
                        acc2[ti][mt] = __builtin_amdgcn_mfma_f32_16x16x32_bf16(
                            afr[mt], bfr, acc2[ti][mt], 0, 0, 0);
                }
            }
        }
        if (c < NCH2 - 1)
            *reinterpret_cast<bf16x8*>(
                &smc[(c + 1) & 1][chadr(sr, sc)]) = pre;
        __syncthreads();
    }

    // core: cols 0..299 = relu(h2), 300=cr, 301=la, 302..319=0
    #pragma unroll
    for (int ti = 0; ti < 3; ++ti) {
        int nt = w + ti * 8;
        if (nt < 19) {
            int c = nt * 16 + l15;
            if (c < 300) {
                float bias = b2[c];
                #pragma unroll
                for (int mt = 0; mt < 4; ++mt)
                    #pragma unroll
                    for (int j = 0; j < 4; ++j) {
                        int r = mt * 16 + lg * 4 + j;
                        smo[r * CO_S + c] =
                            (__bf16)fmaxf(acc2[ti][mt][j] + bias, 0.0f);
                    }
            }
        }
    }
    if (tid < 64) {
        int r = row0 + tid;
        float cr = fminf(fmaxf(reward[r], -1.0f), 1.0f);
        bf16x4 tail;
        tail[0] = (__bf16)cr;
        tail[1] = (__bf16)(float)last_action[r];
        tail[2] = (__bf16)0.0f;
        tail[3] = (__bf16)0.0f;
        *reinterpret_cast<bf16x4*>(&smo[tid * CO_S + 300]) = tail;
        bf16x8 z;
        #pragma unroll
        for (int j = 0; j < 8; ++j) z[j] = (__bf16)0.0f;
        *reinterpret_cast<bf16x8*>(&smo[tid * CO_S + 304]) = z;
        *reinterpret_cast<bf16x8*>(&smo[tid * CO_S + 312]) = z;
    }
    __syncthreads();

    // head: waves 0..3, 16 rows each; lane l15 = output (0:mu,1:sigma,2:bl)
    if (w < 4) {
        f32x4 hac = (f32x4){0.f, 0.f, 0.f, 0.f};
        const float* wsrc = (l15 == 2) ? Wb : (Wp + l15 * CORE);
        #pragma unroll
        for (int ks = 0; ks < 10; ++ks) {
            int kb = ks * 32 + lg * 8;
            bf16x8 afr = *reinterpret_cast<const bf16x8*>(
                &smo[(w * 16 + l15) * CO_S + kb]);
            bf16x8 bfr;
            #pragma unroll
            for (int e = 0; e < 8; ++e) {
                int k = kb + e;
                bfr[e] = (l15 < 3 && k < CORE) ? (__bf16)wsrc[k] : (__bf16)0.0f;
            }
            hac = __builtin_amdgcn_mfma_f32_16x16x32_bf16(afr, bfr, hac, 0, 0, 0);
        }
        float bias = (l15 == 0) ? bp[0] : (l15 == 1) ? bp[1] : (l15 == 2) ? bb[0] : 0.0f;
        #pragma unroll
        for (int j = 0; j < 4; ++j) {
            float v = hac[j] + bias;
            if (l15 < 2) v = 1.0f / (1.0f + __expf(-v));
            float ot = __shfl_xor(v, 1);
            int r = row0 + w * 16 + lg * 4 + j;
            if (l15 == 0) {
                out[(size_t)r * 4 + 0] = v;
                out[(size_t)r * 4 + 3] = fmaf(ot, eps[r], v);
            } else if (l15 == 1) {
                out[(size_t)r * 4 + 1] = v;
            } else if (l15 == 2) {
                out[(size_t)r * 4 + 2] = v;
            }
        }
    }
}

// ================= Fused fallback (exact round-3 champion) ===================
template <bool WBF16>
__global__ __launch_bounds__(512, 4) void autoprune_fused(
    const float* __restrict__ frame, const float* __restrict__ reward,
    const int*   __restrict__ last_action, const float* __restrict__ eps,
    const float* __restrict__ W1f, const float* __restrict__ b1,
    const float* __restrict__ W2f, const float* __restrict__ b2,
    const float* __restrict__ Wp, const float* __restrict__ bp,
    const float* __restrict__ Wb, const float* __restrict__ bb,
    const __bf16* __restrict__ W1b, const __bf16* __restrict__ W2b,
    float* __restrict__ out)
{
    __shared__ __bf16 sm_chunk[2][64 * FCH_S];
    __shared__ __bf16 sm_h1[64 * H1_S];
    __shared__ float  sm_res[64][4];
    __bf16* sm_core = sm_h1;

    const int tid  = threadIdx.x;
    const int w    = tid >> 6;
    const int l15  = tid & 15;
    const int lg   = (tid & 63) >> 4;
    const int row0 = blockIdx.x * 64;

    const int sr = tid >> 3;
    const int sc = (tid & 7) * 8;
    const float* fbase = frame + (size_t)(row0 + sr) * OBS + sc;

    {
        float4 a = *reinterpret_cast<const float4*>(fbase);
        float4 b = *reinterpret_cast<const float4*>(fbase + 4);
        if (tid < 192) {
            int r = tid / 3, c = 400 + (tid % 3) * 8;
            bf16x8 z;
            #pragma unroll
            for (int j = 0; j < 8; ++j) z[j] = (__bf16)0.0f;
            *reinterpret_cast<bf16x8*>(&sm_h1[r * H1_S + c]) = z;
        }
        *reinterpret_cast<bf16x8*>(&sm_chunk[0][sr * FCH_S + sc]) = cvt8(a, b);
    }
    __syncthreads();

    {
        f32x4 acc[4][4];
        #pragma unroll
        for (int a = 0; a < 4; ++a)
            #pragma unroll
            for (int b = 0; b < 4; ++b) acc[a][b] = (f32x4){0.f, 0.f, 0.f, 0.f};

        for (int c = 0; c < NCHUNK; ++c) {
            float4 pa, pb;
            if (c < NCHUNK - 1) {
                pa = *reinterpret_cast<const float4*>(fbase + (c + 1) * CH_K);
                pb = *reinterpret_cast<const float4*>(fbase + (c + 1) * CH_K + 4);
            }
            const __bf16* buf = sm_chunk[c & 1];
            #pragma unroll
            for (int ks = 0; ks < 2; ++ks) {
                const int kl = ks * 32 + lg * 8;
                bf16x8 afr[4];
                #pragma unroll
                for (int mt = 0; mt < 4; ++mt)
                    afr[mt] = *reinterpret_cast<const bf16x8*>(
                        &buf[(mt * 16 + l15) * FCH_S + kl]);
                const int kg = c * CH_K + kl;
                #pragma unroll
                for (int ti = 0; ti < 4; ++ti) {
                    int nt = w + ti * 8;
                    if (nt < 25) {
                        bf16x8 bfr;
                        if constexpr (WBF16) {
                            bfr = *reinterpret_cast<const bf16x8*>(
                                W1b + (size_t)(nt * 16 + l15) * OBS + kg);
                        } else {
                            const float4* wp = reinterpret_cast<const float4*>(
                                W1f + (size_t)(nt * 16 + l15) * OBS + kg);
                            bfr = cvt8(wp[0], wp[1]);
                        }
                        #pragma unroll
                        for (int mt = 0; mt < 4; ++mt)
                            acc[ti][mt] = __builtin_amdgcn_mfma_f32_16x16x32_bf16(
                                afr[mt], bfr, acc[ti][mt], 0, 0, 0);
                    }
                }
            }
            if (c < NCHUNK - 1)
                *reinterpret_cast<bf16x8*>(
                    &sm_chunk[(c + 1) & 1][sr * FCH_S + sc]) = cvt8(pa, pb);
            __syncthreads();
        }

        #pragma unroll
        for (int ti = 0; ti < 4; ++ti) {
            int nt = w + ti * 8;
            if (nt < 25) {
                int c = nt * 16 + l15;
                float bias = b1[c];
                #pragma unroll
                for (int mt = 0; mt < 4; ++mt)
                    #pragma unroll
                    for (int j = 0; j < 4; ++j) {
                        int r = mt * 16 + lg * 4 + j;
                        sm_h1[r * H1_S + c] =
                            (__bf16)fmaxf(acc[ti][mt][j] + bias, 0.0f);
                    }
            }
        }
    }
    __syncthreads();

    f32x4 acc2[3][4];
    #pragma unroll
    for (int a = 0; a < 3; ++a)
        #pragma unroll
        for (int b = 0; b < 4; ++b) acc2[a][b] = (f32x4){0.f, 0.f, 0.f, 0.f};

    #pragma unroll 2
    for (int ks = 0; ks < 13; ++ks) {
        const int kb = ks * 32 + lg * 8;
        bf16x8 afr[4];
        #pragma unroll
        for (int mt = 0; mt < 4; ++mt)
            afr[mt] = *reinterpret_cast<const bf16x8*>(
                &sm_h1[(mt * 16 + l15) * H1_S + kb]);
        const int kbw = (kb >= 400) ? 0 : kb;
        #pragma unroll
        for (int ti = 0; ti < 3; ++ti) {
            int nt = w + ti * 8;
            if (nt < 19) {
                int cc = nt * 16 + l15;
                if (cc >= 300) cc = 299;
                bf16x8 bfr;
                if constexpr (WBF16) {
                    bfr = *reinterpret_cast<const bf16x8*>(
                        W2b + (size_t)cc * H1N + kbw);
                } else {
                    const float4* wp = reinterpret_cast<const float4*>(
                        W2f + (size_t)cc * H1N + kbw);
                    bfr = cvt8(wp[0], wp[1]);
                }
                #pragma unroll
                for (int mt = 0; mt < 4; ++mt)
                    acc2[ti][mt] = __builtin_amdgcn_mfma_f32_16x16x32_bf16(
                        afr[mt], bfr, acc2[ti][mt], 0, 0, 0);
            }
        }
    }
    __syncthreads();

    #pragma unroll
    for (int ti = 0; ti < 3; ++ti) {
        int nt = w + ti * 8;
        if (nt < 19) {
            int c = nt * 16 + l15;
            if (c < 300) {
                float bias = b2[c];
                #pragma unroll
                for (int mt = 0; mt < 4; ++mt)
                    #pragma unroll
                    for (int j = 0; j < 4; ++j) {
                        int r = mt * 16 + lg * 4 + j;
                        sm_core[r * H1_S + c] =
                            (__bf16)fmaxf(acc2[ti][mt][j] + bias, 0.0f);
                    }
            }
        }
    }
    if (tid < 64) {
        int r = row0 + tid;
        float cr = fminf(fmaxf(reward[r], -1.0f), 1.0f);
        bf16x4 tail;
        tail[0] = (__bf16)cr;
        tail[1] = (__bf16)(float)last_action[r];
        tail[2] = (__bf16)0.0f;
        tail[3] = (__bf16)0.0f;
        *reinterpret_cast<bf16x4*>(&sm_core[tid * H1_S + 300]) = tail;
        bf16x8 z;
        #pragma unroll
        for (int j = 0; j < 8; ++j) z[j] = (__bf16)0.0f;
        *reinterpret_cast<bf16x8*>(&sm_core[tid * H1_S + 304]) = z;
        *reinterpret_cast<bf16x8*>(&sm_core[tid * H1_S + 312]) = z;
    }
    __syncthreads();

    if (w < 4) {
        f32x4 hac = (f32x4){0.f, 0.f, 0.f, 0.f};
        const float* wsrc = (l15 == 2) ? Wb : (Wp + l15 * CORE);
        #pragma unroll
        for (int ks = 0; ks < 10; ++ks) {
            int kb = ks * 32 + lg * 8;
            bf16x8 afr = *reinterpret_cast<const bf16x8*>(
                &sm_core[(w * 16 + l15) * H1_S + kb]);
            bf16x8 bfr;
            #pragma unroll
            for (int e = 0; e < 8; ++e) {
                int k = kb + e;
                bfr[e] = (l15 < 3 && k < CORE) ? (__bf16)wsrc[k] : (__bf16)0.0f;
            }
            hac = __builtin_amdgcn_mfma_f32_16x16x32_bf16(afr, bfr, hac, 0, 0, 0);
        }
        float bias = (l15 == 0) ? bp[0] : (l15 == 1) ? bp[1] : (l15 == 2) ? bb[0] : 0.0f;
        #pragma unroll
        for (int j = 0; j < 4; ++j) {
            float v = hac[j] + bias;
            if (l15 < 2) v = 1.0f / (1.0f + __expf(-v));
            float ot = __shfl_xor(v, 1);
            int r = row0 + w * 16 + lg * 4 + j;
            if (l15 == 0) {
                out[(size_t)r * 4 + 0] = v;
                out[(size_t)r * 4 + 3] = fmaf(ot, eps[r], v);
            } else if (l15 == 1) {
                out[(size_t)r * 4 + 1] = v;
            } else if (l15 == 2) {
                out[(size_t)r * 4 + 2] = v;
            }
        }
    }
}

extern "C" void kernel_launch(void* const* d_in, const int* in_sizes, int n_in,
                              void* d_out, int out_size, void* d_ws, size_t ws_size,
                              hipStream_t stream) {
    const float* frame       = (const float*)d_in[0];
    const float* reward      = (const float*)d_in[1];
    const int*   last_action = (const int*)  d_in[2];
    const float* eps         = (const float*)d_in[3];
    const float* W1          = (const float*)d_in[4];
    const float* b1          = (const float*)d_in[5];
    const float* W2          = (const float*)d_in[6];
    const float* b2          = (const float*)d_in[7];
    const float* Wp          = (const float*)d_in[8];
    const float* bp          = (const float*)d_in[9];
    const float* Wb          = (const float*)d_in[10];
    const float* bb          = (const float*)d_in[11];
    float* out = (float*)d_out;

    const size_t wbytes  = (size_t)(H1N * OBS + H2N * H1N) * 2;    // 649,600
    const size_t h1_off  = 655360;                                 // 16B-aligned
    const size_t h1bytes = (size_t)TBR * H1G_S * 2;                // 117,440,512
    dim3 grid(TBR / 64);   // 2048 blocks, 512 threads

    if (ws_size >= h1_off + h1bytes) {
        // -------- split pipeline: conv -> gemm1 -> gemm2+head --------
        __bf16* wsb = (__bf16*)d_ws;
        __bf16* h1g = (__bf16*)((char*)d_ws + h1_off);
        int nconv = (H1N * OBS + H2N * H1N) / 8;                   // 40600
        conv_weights<<<(nconv + 255) / 256, 256, 0, stream>>>(W1, W2, wsb);
        gemm1<<<grid, 512, 0, stream>>>(frame, wsb, b1, h1g);
        gemm2_head<<<grid, 512, 0, stream>>>(
            h1g, wsb + H1N * OBS, b2, reward, last_action, eps,
            Wp, bp, Wb, bb, out);
    } else if (ws_size >= wbytes) {
        __bf16* wsb = (__bf16*)d_ws;
        int nconv = (H1N * OBS + H2N * H1N) / 8;
        conv_weights<<<(nconv + 255) / 256, 256, 0, stream>>>(W1, W2, wsb);
        autoprune_fused<true><<<grid, 512, 0, stream>>>(
            frame, reward, last_action, eps, W1, b1, W2, b2, Wp, bp, Wb, bb,
            (const __bf16*)wsb, (const __bf16*)(wsb + H1N * OBS), out);
    } else {
        autoprune_fused<false><<<grid, 512, 0, stream>>>(
            frame, reward, last_action, eps, W1, b1, W2, b2, Wp, bp, Wb, bb,
            (const __bf16*)nullptr, (const __bf16*)nullptr, out);
    }
}